// Round 3
// baseline (116.451 us; speedup 1.0000x reference)
//
#include <hip/hip_runtime.h>

// LeakyIntegrator: T=64 scan, independent per (c,h,w) element.
// m_t = r ? img : (a ? m + lam*cov*(img - m) : m)        [algebraic lerp form]
// c_t = r ? cov : (a ? clip(c+cov,0,1) : c),   reset[0] forced true.
//
// One fused kernel: thread per (c,h,w/4) column; c==0 blocks also carry the
// coverage recurrence. Depth-4 prefetch, full unroll (compile-time buffer
// indices -> registers, no scratch), nontemporal img loads / out stores.

#define LAM 0.2f
#define T_STEPS 64
#define C_CH 64
#define H_DIM 128
#define W_DIM 128
#define HW (H_DIM * W_DIM)            // 16384
#define CHW (C_CH * HW)               // 1048576
#define MAPS_SIZE ((size_t)T_STEPS * CHW)
#define PFD 4                         // prefetch depth

typedef float f32x4 __attribute__((ext_vector_type(4)));

// T == wave width: lane t loads mask[t], ballot packs the 64 bools.
// add_mask is all-True by construction -> first 4 bytes disambiguate
// int32 bools (0x00000001) vs byte bools (0x01010101).
__device__ __forceinline__ void load_masks_ballot(const void* add_p, const void* reset_p,
                                                  unsigned long long& abits,
                                                  unsigned long long& rbits) {
    const int lane = threadIdx.x & 63;
    const unsigned int w0 = *(const unsigned int*)add_p;
    int av, rv;
    if (w0 == 1u) {  // int32 bools
        av = ((const int*)add_p)[lane];
        rv = ((const int*)reset_p)[lane];
    } else {         // byte bools
        av = ((const unsigned char*)add_p)[lane];
        rv = ((const unsigned char*)reset_p)[lane];
    }
    abits = __ballot(av != 0);
    rbits = __ballot(rv != 0) | 1ull;   // step 0 always resets
}

__global__ __launch_bounds__(256, 4) void li_fused_kernel(
        const float* __restrict__ img, const float* __restrict__ cov,
        const void* __restrict__ addm, const void* __restrict__ resetm,
        float* __restrict__ out) {
    const int tid  = blockIdx.x * 256 + threadIdx.x;   // 0 .. CHW/4-1
    const int pix4 = tid & (HW / 4 - 1);               // 0..4095
    const int c    = tid >> 12;                        // 0..63
    const int base    = c * HW + pix4 * 4;
    const int covbase = pix4 * 4;
    const bool do_cov = (c == 0);                      // blocks 0..15, block-uniform

    unsigned long long abits, rbits;
    load_masks_ballot(addm, resetm, abits, rbits);

    const float* ip  = img + base;
    const float* cp  = cov + covbase;
    float*       mop = out + base;
    float*       cop = out + MAPS_SIZE + covbase;

    // depth-4 prefetch; all indices compile-time after full unroll.
    f32x4 imb[PFD], cvb[PFD];
    #pragma unroll
    for (int t = 0; t < PFD; ++t) {
        imb[t] = __builtin_nontemporal_load((const f32x4*)(ip + (size_t)t * CHW));
        cvb[t] = *(const f32x4*)(cp + (size_t)t * HW);
    }

    f32x4 m  = (f32x4)(0.f);
    f32x4 cc = (f32x4)(0.f);

    #pragma unroll
    for (int t = 0; t < T_STEPS; ++t) {
        const f32x4 im = imb[t % PFD];
        const f32x4 cv = cvb[t % PFD];
        if (t + PFD < T_STEPS) {
            imb[t % PFD] = __builtin_nontemporal_load((const f32x4*)(ip + (size_t)(t + PFD) * CHW));
            cvb[t % PFD] = *(const f32x4*)(cp + (size_t)(t + PFD) * HW);
        }
        const bool r = (rbits >> t) & 1ull;
        const bool a = (abits >> t) & 1ull;

        // m_upd = (1-lam)m + lam*img*cov + lam*m*(1-cov)  ==  m + lam*cov*(img-m)
        f32x4 mu;
        mu.x = fmaf(LAM * cv.x, im.x - m.x, m.x);
        mu.y = fmaf(LAM * cv.y, im.y - m.y, m.y);
        mu.z = fmaf(LAM * cv.z, im.z - m.z, m.z);
        mu.w = fmaf(LAM * cv.w, im.w - m.w, m.w);

        m.x = r ? im.x : (a ? mu.x : m.x);
        m.y = r ? im.y : (a ? mu.y : m.y);
        m.z = r ? im.z : (a ? mu.z : m.z);
        m.w = r ? im.w : (a ? mu.w : m.w);

        __builtin_nontemporal_store(m, (f32x4*)(mop + (size_t)t * CHW));

        if (do_cov) {
            f32x4 cu;
            cu.x = fminf(fmaxf(cc.x + cv.x, 0.f), 1.f);
            cu.y = fminf(fmaxf(cc.y + cv.y, 0.f), 1.f);
            cu.z = fminf(fmaxf(cc.z + cv.z, 0.f), 1.f);
            cu.w = fminf(fmaxf(cc.w + cv.w, 0.f), 1.f);
            cc.x = r ? cv.x : (a ? cu.x : cc.x);
            cc.y = r ? cv.y : (a ? cu.y : cc.y);
            cc.z = r ? cv.z : (a ? cu.z : cc.z);
            cc.w = r ? cv.w : (a ? cu.w : cc.w);
            __builtin_nontemporal_store(cc, (f32x4*)(cop + (size_t)t * HW));
        }
    }
}

extern "C" void kernel_launch(void* const* d_in, const int* in_sizes, int n_in,
                              void* d_out, int out_size, void* d_ws, size_t ws_size,
                              hipStream_t stream) {
    const float* img    = (const float*)d_in[0];
    const float* cov    = (const float*)d_in[1];
    const void*  addm   = d_in[2];
    const void*  resetm = d_in[3];
    float* out = (float*)d_out;

    li_fused_kernel<<<(CHW / 4) / 256, 256, 0, stream>>>(img, cov, addm, resetm, out);
}

// Round 4
// 107.532 us; speedup vs baseline: 1.0829x; 1.0829x over previous
//
#include <hip/hip_runtime.h>

// LeakyIntegrator: T=64 scan, independent per (c,h,w) element.
// m_t = r ? img : (a ? m + lam*cov*(img - m) : m)        [algebraic lerp form]
// c_t = r ? cov : (a ? clip(c+cov,0,1) : c),   reset[0] forced true.
//
// One fused kernel: thread per (c,h,w/2) float2 column -> 2048 blocks,
// 32 waves/CU (8/SIMD) for issue interleave. c==0 blocks also carry the
// coverage recurrence. Depth-2 prefetch, full unroll, nontemporal stream.

#define LAM 0.2f
#define T_STEPS 64
#define C_CH 64
#define H_DIM 128
#define W_DIM 128
#define HW (H_DIM * W_DIM)            // 16384
#define CHW (C_CH * HW)               // 1048576
#define MAPS_SIZE ((size_t)T_STEPS * CHW)
#define PFD 2                         // prefetch depth (depth-4 regressed: R2)

typedef float f32x2 __attribute__((ext_vector_type(2)));

// T == wave width: lane t loads mask[t], ballot packs the 64 bools.
// add_mask is all-True by construction -> first 4 bytes disambiguate
// int32 bools (0x00000001) vs byte bools (0x01010101).
__device__ __forceinline__ void load_masks_ballot(const void* add_p, const void* reset_p,
                                                  unsigned long long& abits,
                                                  unsigned long long& rbits) {
    const int lane = threadIdx.x & 63;
    const unsigned int w0 = *(const unsigned int*)add_p;
    int av, rv;
    if (w0 == 1u) {  // int32 bools
        av = ((const int*)add_p)[lane];
        rv = ((const int*)reset_p)[lane];
    } else {         // byte bools
        av = ((const unsigned char*)add_p)[lane];
        rv = ((const unsigned char*)reset_p)[lane];
    }
    abits = __ballot(av != 0);
    rbits = __ballot(rv != 0) | 1ull;   // step 0 always resets
}

__global__ __launch_bounds__(256, 8) void li_fused_kernel(
        const float* __restrict__ img, const float* __restrict__ cov,
        const void* __restrict__ addm, const void* __restrict__ resetm,
        float* __restrict__ out) {
    const int tid  = blockIdx.x * 256 + threadIdx.x;   // 0 .. CHW/2-1
    const int pix2 = tid & (HW / 2 - 1);               // 0..8191
    const int c    = tid >> 13;                        // 0..63
    const int base    = c * HW + pix2 * 2;
    const int covbase = pix2 * 2;
    const bool do_cov = (c == 0);                      // blocks 0..31, block-uniform

    unsigned long long abits, rbits;
    load_masks_ballot(addm, resetm, abits, rbits);

    const float* ip  = img + base;
    const float* cp  = cov + covbase;
    float*       mop = out + base;
    float*       cop = out + MAPS_SIZE + covbase;

    // depth-2 prefetch; all indices compile-time after full unroll.
    f32x2 imb[PFD], cvb[PFD];
    #pragma unroll
    for (int t = 0; t < PFD; ++t) {
        imb[t] = __builtin_nontemporal_load((const f32x2*)(ip + (size_t)t * CHW));
        cvb[t] = *(const f32x2*)(cp + (size_t)t * HW);
    }

    f32x2 m  = (f32x2)(0.f);
    f32x2 cc = (f32x2)(0.f);

    #pragma unroll
    for (int t = 0; t < T_STEPS; ++t) {
        const f32x2 im = imb[t % PFD];
        const f32x2 cv = cvb[t % PFD];
        if (t + PFD < T_STEPS) {
            imb[t % PFD] = __builtin_nontemporal_load((const f32x2*)(ip + (size_t)(t + PFD) * CHW));
            cvb[t % PFD] = *(const f32x2*)(cp + (size_t)(t + PFD) * HW);
        }
        const bool r = (rbits >> t) & 1ull;
        const bool a = (abits >> t) & 1ull;

        // m_upd = (1-lam)m + lam*img*cov + lam*m*(1-cov)  ==  m + lam*cov*(img-m)
        f32x2 mu;
        mu.x = fmaf(LAM * cv.x, im.x - m.x, m.x);
        mu.y = fmaf(LAM * cv.y, im.y - m.y, m.y);

        m.x = r ? im.x : (a ? mu.x : m.x);
        m.y = r ? im.y : (a ? mu.y : m.y);

        __builtin_nontemporal_store(m, (f32x2*)(mop + (size_t)t * CHW));

        if (do_cov) {
            f32x2 cu;
            cu.x = fminf(fmaxf(cc.x + cv.x, 0.f), 1.f);
            cu.y = fminf(fmaxf(cc.y + cv.y, 0.f), 1.f);
            cc.x = r ? cv.x : (a ? cu.x : cc.x);
            cc.y = r ? cv.y : (a ? cu.y : cc.y);
            __builtin_nontemporal_store(cc, (f32x2*)(cop + (size_t)t * HW));
        }
    }
}

extern "C" void kernel_launch(void* const* d_in, const int* in_sizes, int n_in,
                              void* d_out, int out_size, void* d_ws, size_t ws_size,
                              hipStream_t stream) {
    const float* img    = (const float*)d_in[0];
    const float* cov    = (const float*)d_in[1];
    const void*  addm   = d_in[2];
    const void*  resetm = d_in[3];
    float* out = (float*)d_out;

    li_fused_kernel<<<(CHW / 2) / 256, 256, 0, stream>>>(img, cov, addm, resetm, out);
}

// Round 5
// 95.059 us; speedup vs baseline: 1.2250x; 1.1312x over previous
//
#include <hip/hip_runtime.h>

// LeakyIntegrator: T=64 scan, independent per (c,h,w) element.
// m_t = r ? img : (a ? m + lam*cov*(img - m) : m)        [algebraic lerp form]
// c_t = r ? cov : (a ? clip(c+cov,0,1) : c),   reset[0] forced true.
//
// One fused kernel: thread per (c,h,w/2) float2 column, 32 waves/CU.
// c==0 blocks also carry the coverage recurrence. Depth-2 prefetch, full
// unroll. nt LOADS on img (keep L2 for cov); PLAIN stores (L2 write
// coalescing -> better DRAM drain than nt-bypass; fill kernel evidence).

#define LAM 0.2f
#define T_STEPS 64
#define C_CH 64
#define H_DIM 128
#define W_DIM 128
#define HW (H_DIM * W_DIM)            // 16384
#define CHW (C_CH * HW)               // 1048576
#define MAPS_SIZE ((size_t)T_STEPS * CHW)
#define PFD 2                         // prefetch depth (depth-4 regressed: R2)

typedef float f32x2 __attribute__((ext_vector_type(2)));

// T == wave width: lane t loads mask[t], ballot packs the 64 bools.
// add_mask is all-True by construction -> first 4 bytes disambiguate
// int32 bools (0x00000001) vs byte bools (0x01010101).
__device__ __forceinline__ void load_masks_ballot(const void* add_p, const void* reset_p,
                                                  unsigned long long& abits,
                                                  unsigned long long& rbits) {
    const int lane = threadIdx.x & 63;
    const unsigned int w0 = *(const unsigned int*)add_p;
    int av, rv;
    if (w0 == 1u) {  // int32 bools
        av = ((const int*)add_p)[lane];
        rv = ((const int*)reset_p)[lane];
    } else {         // byte bools
        av = ((const unsigned char*)add_p)[lane];
        rv = ((const unsigned char*)reset_p)[lane];
    }
    abits = __ballot(av != 0);
    rbits = __ballot(rv != 0) | 1ull;   // step 0 always resets
}

__global__ __launch_bounds__(256, 8) void li_fused_kernel(
        const float* __restrict__ img, const float* __restrict__ cov,
        const void* __restrict__ addm, const void* __restrict__ resetm,
        float* __restrict__ out) {
    const int tid  = blockIdx.x * 256 + threadIdx.x;   // 0 .. CHW/2-1
    const int pix2 = tid & (HW / 2 - 1);               // 0..8191
    const int c    = tid >> 13;                        // 0..63
    const int base    = c * HW + pix2 * 2;
    const int covbase = pix2 * 2;
    const bool do_cov = (c == 0);                      // blocks 0..31, block-uniform

    unsigned long long abits, rbits;
    load_masks_ballot(addm, resetm, abits, rbits);

    const float* ip  = img + base;
    const float* cp  = cov + covbase;
    float*       mop = out + base;
    float*       cop = out + MAPS_SIZE + covbase;

    // depth-2 prefetch; all indices compile-time after full unroll.
    f32x2 imb[PFD], cvb[PFD];
    #pragma unroll
    for (int t = 0; t < PFD; ++t) {
        imb[t] = __builtin_nontemporal_load((const f32x2*)(ip + (size_t)t * CHW));
        cvb[t] = *(const f32x2*)(cp + (size_t)t * HW);
    }

    f32x2 m  = (f32x2)(0.f);
    f32x2 cc = (f32x2)(0.f);

    #pragma unroll
    for (int t = 0; t < T_STEPS; ++t) {
        const f32x2 im = imb[t % PFD];
        const f32x2 cv = cvb[t % PFD];
        if (t + PFD < T_STEPS) {
            imb[t % PFD] = __builtin_nontemporal_load((const f32x2*)(ip + (size_t)(t + PFD) * CHW));
            cvb[t % PFD] = *(const f32x2*)(cp + (size_t)(t + PFD) * HW);
        }
        const bool r = (rbits >> t) & 1ull;
        const bool a = (abits >> t) & 1ull;

        // m_upd = (1-lam)m + lam*img*cov + lam*m*(1-cov)  ==  m + lam*cov*(img-m)
        f32x2 mu;
        mu.x = fmaf(LAM * cv.x, im.x - m.x, m.x);
        mu.y = fmaf(LAM * cv.y, im.y - m.y, m.y);

        m.x = r ? im.x : (a ? mu.x : m.x);
        m.y = r ? im.y : (a ? mu.y : m.y);

        *(f32x2*)(mop + (size_t)t * CHW) = m;   // plain store: L2 write-coalesce

        if (do_cov) {
            f32x2 cu;
            cu.x = fminf(fmaxf(cc.x + cv.x, 0.f), 1.f);
            cu.y = fminf(fmaxf(cc.y + cv.y, 0.f), 1.f);
            cc.x = r ? cv.x : (a ? cu.x : cc.x);
            cc.y = r ? cv.y : (a ? cu.y : cc.y);
            *(f32x2*)(cop + (size_t)t * HW) = cc;
        }
    }
}

extern "C" void kernel_launch(void* const* d_in, const int* in_sizes, int n_in,
                              void* d_out, int out_size, void* d_ws, size_t ws_size,
                              hipStream_t stream) {
    const float* img    = (const float*)d_in[0];
    const float* cov    = (const float*)d_in[1];
    const void*  addm   = d_in[2];
    const void*  resetm = d_in[3];
    float* out = (float*)d_out;

    li_fused_kernel<<<(CHW / 2) / 256, 256, 0, stream>>>(img, cov, addm, resetm, out);
}